// Round 1
// baseline (724.757 us; speedup 1.0000x reference)
//
#include <hip/hip_runtime.h>

#define NUM_USERS 100000
#define NUM_ITEMS 50000
#define N_NODES   150000   // NUM_USERS + NUM_ITEMS
#define DIM       64
#define NNZ       1000000
#define BATCH     4096
#define N_LAYERS  3

// ---------------------------------------------------------------------------
// init: x = concat(user_emb, item_emb); acc = x   (float4 grid-stride)
// ---------------------------------------------------------------------------
__global__ void init_kernel(const float* __restrict__ user_emb,
                            const float* __restrict__ item_emb,
                            float* __restrict__ x,
                            float* __restrict__ acc) {
    const int64_t total4 = (int64_t)N_NODES * DIM / 4;      // 2.4M float4
    const int64_t user4  = (int64_t)NUM_USERS * DIM / 4;    // 1.6M float4
    int64_t stride = (int64_t)gridDim.x * blockDim.x;
    for (int64_t i = (int64_t)blockIdx.x * blockDim.x + threadIdx.x;
         i < total4; i += stride) {
        float4 v = (i < user4) ? ((const float4*)user_emb)[i]
                               : ((const float4*)item_emb)[i - user4];
        ((float4*)x)[i]   = v;
        ((float4*)acc)[i] = v;
    }
}

// ---------------------------------------------------------------------------
// SpMM (COO, atomic scatter): one wave (64 lanes) per edge, lane = dim.
// y[r, lane] += v * x[c, lane]
// ---------------------------------------------------------------------------
__global__ void spmm_kernel(const int*   __restrict__ rows,
                            const int*   __restrict__ cols,
                            const float* __restrict__ vals,
                            const float* __restrict__ x,
                            float*       __restrict__ y) {
    const int lane   = threadIdx.x & 63;
    const int wave   = (int)((blockIdx.x * blockDim.x + threadIdx.x) >> 6);
    const int nwaves = (int)((gridDim.x * blockDim.x) >> 6);
    for (int e = wave; e < NNZ; e += nwaves) {
        int   r = rows[e];
        int   c = cols[e];
        float v = vals[e];
        float xv = x[(int64_t)c * DIM + lane];
        unsafeAtomicAdd(&y[(int64_t)r * DIM + lane], v * xv);
    }
}

// ---------------------------------------------------------------------------
// acc += y   (float4 grid-stride)
// ---------------------------------------------------------------------------
__global__ void add_kernel(float* __restrict__ acc, const float* __restrict__ y) {
    const int64_t total4 = (int64_t)N_NODES * DIM / 4;
    int64_t stride = (int64_t)gridDim.x * blockDim.x;
    for (int64_t i = (int64_t)blockIdx.x * blockDim.x + threadIdx.x;
         i < total4; i += stride) {
        float4 a = ((float4*)acc)[i];
        float4 b = ((const float4*)y)[i];
        a.x += b.x; a.y += b.y; a.z += b.z; a.w += b.w;
        ((float4*)acc)[i] = a;
    }
}

// ---------------------------------------------------------------------------
// output: one wave per batch element.
//   user  = acc[user_idx[b]] / 4            -> out[BATCH + b*64 + lane]
//   item  = acc[NUM_USERS + item_idx[b]]/4  -> out[BATCH + BATCH*64 + b*64 + lane]
//   rating= dot(user, item)                 -> out[b]
// ---------------------------------------------------------------------------
__global__ void out_kernel(const int* __restrict__ user_idx,
                           const int* __restrict__ item_idx,
                           const float* __restrict__ acc,
                           float* __restrict__ out) {
    const int lane = threadIdx.x & 63;
    const int wave = (int)((blockIdx.x * blockDim.x + threadIdx.x) >> 6);
    if (wave >= BATCH) return;
    int u = user_idx[wave];
    int t = item_idx[wave];
    float uv = acc[(int64_t)u * DIM + lane] * 0.25f;
    float iv = acc[(int64_t)(NUM_USERS + t) * DIM + lane] * 0.25f;
    out[(int64_t)BATCH + (int64_t)wave * DIM + lane] = uv;
    out[(int64_t)BATCH + (int64_t)BATCH * DIM + (int64_t)wave * DIM + lane] = iv;
    float p = uv * iv;
    #pragma unroll
    for (int off = 32; off >= 1; off >>= 1) p += __shfl_down(p, off, 64);
    if (lane == 0) out[wave] = p;
}

// ---------------------------------------------------------------------------
extern "C" void kernel_launch(void* const* d_in, const int* in_sizes, int n_in,
                              void* d_out, int out_size, void* d_ws, size_t ws_size,
                              hipStream_t stream) {
    const int*   user_idx = (const int*)  d_in[0];
    const int*   item_idx = (const int*)  d_in[1];
    const int*   rows     = (const int*)  d_in[2];
    const int*   cols     = (const int*)  d_in[3];
    const float* vals     = (const float*)d_in[4];
    const float* user_emb = (const float*)d_in[5];
    const float* item_emb = (const float*)d_in[6];
    float*       out      = (float*)d_out;

    const size_t nfloats = (size_t)N_NODES * DIM;           // 9.6M
    const size_t nbytes  = nfloats * sizeof(float);          // 38.4MB
    float* buf0 = (float*)d_ws;                              // x / y ping-pong
    float* buf1 = (float*)((char*)d_ws + nbytes);
    float* acc  = (float*)((char*)d_ws + 2 * nbytes);

    const int TB = 256;
    const int gridElem = 2048;   // grid-stride elementwise kernels
    const int gridSpmm = 4096;   // 16384 waves over 1e6 edges

    // x = concat embeddings; acc = x
    init_kernel<<<gridElem, TB, 0, stream>>>(user_emb, item_emb, buf0, acc);

    float* x = buf0;
    float* y = buf1;
    for (int layer = 0; layer < N_LAYERS; ++layer) {
        hipMemsetAsync(y, 0, nbytes, stream);
        spmm_kernel<<<gridSpmm, TB, 0, stream>>>(rows, cols, vals, x, y);
        add_kernel<<<gridElem, TB, 0, stream>>>(acc, y);
        float* tmp = x; x = y; y = tmp;
    }

    out_kernel<<<(BATCH * 64 + TB - 1) / TB, TB, 0, stream>>>(user_idx, item_idx, acc, out);
}

// Round 2
// 356.394 us; speedup vs baseline: 2.0336x; 2.0336x over previous
//
#include <hip/hip_runtime.h>

#define NUM_USERS 100000
#define NUM_ITEMS 50000
#define N_NODES   150000   // NUM_USERS + NUM_ITEMS
#define DIM       64
#define NNZ       1000000
#define BATCH     4096
#define N_LAYERS  3

#define SCAN_B 512
#define NBLK ((N_NODES + SCAN_B - 1) / SCAN_B)   // 293

// ---------------------------------------------------------------------------
// CSR build step 1: histogram of row degrees
// ---------------------------------------------------------------------------
__global__ void hist_kernel(const int* __restrict__ rows, int* __restrict__ cnt) {
    int stride = gridDim.x * blockDim.x;
    for (int e = blockIdx.x * blockDim.x + threadIdx.x; e < NNZ; e += stride)
        atomicAdd(&cnt[rows[e]], 1);
}

// ---------------------------------------------------------------------------
// CSR build step 2a: per-block inclusive scan (512 elems/block);
// writes block-local EXCLUSIVE scan to rowptr, block total to blksum.
// ---------------------------------------------------------------------------
__global__ __launch_bounds__(SCAN_B) void scan_block_kernel(
        const int* __restrict__ cnt, int* __restrict__ rowptr,
        int* __restrict__ blksum) {
    __shared__ int sh[SCAN_B];
    int i = blockIdx.x * SCAN_B + threadIdx.x;
    int v = (i < N_NODES) ? cnt[i] : 0;
    sh[threadIdx.x] = v;
    __syncthreads();
    for (int off = 1; off < SCAN_B; off <<= 1) {
        int t = (threadIdx.x >= off) ? sh[threadIdx.x - off] : 0;
        __syncthreads();
        sh[threadIdx.x] += t;
        __syncthreads();
    }
    if (i < N_NODES) rowptr[i] = sh[threadIdx.x] - v;        // exclusive, block-local
    if (threadIdx.x == SCAN_B - 1) blksum[blockIdx.x] = sh[SCAN_B - 1];
}

// ---------------------------------------------------------------------------
// CSR build step 2b: single-block scan of block sums -> exclusive offsets
// ---------------------------------------------------------------------------
__global__ __launch_bounds__(SCAN_B) void scan_top_kernel(int* __restrict__ blksum) {
    __shared__ int sh[SCAN_B];
    int v = (threadIdx.x < NBLK) ? blksum[threadIdx.x] : 0;
    sh[threadIdx.x] = v;
    __syncthreads();
    for (int off = 1; off < SCAN_B; off <<= 1) {
        int t = (threadIdx.x >= off) ? sh[threadIdx.x - off] : 0;
        __syncthreads();
        sh[threadIdx.x] += t;
        __syncthreads();
    }
    if (threadIdx.x < NBLK) blksum[threadIdx.x] = sh[threadIdx.x] - v;  // exclusive
}

// ---------------------------------------------------------------------------
// CSR build step 2c: add block offsets; init cursor; set rowptr[N]=NNZ
// ---------------------------------------------------------------------------
__global__ void scan_fix_kernel(int* __restrict__ rowptr,
                                const int* __restrict__ blksum,
                                int* __restrict__ cursor) {
    int i = blockIdx.x * blockDim.x + threadIdx.x;
    if (i < N_NODES) {
        int r = rowptr[i] + blksum[i / SCAN_B];
        rowptr[i] = r;
        cursor[i] = r;
    }
    if (i == 0) rowptr[N_NODES] = NNZ;
}

// ---------------------------------------------------------------------------
// CSR build step 3: scatter edges into CSR slots
// ---------------------------------------------------------------------------
__global__ void scatter_kernel(const int* __restrict__ rows,
                               const int* __restrict__ cols,
                               const float* __restrict__ vals,
                               int* __restrict__ cursor,
                               int* __restrict__ csr_col,
                               float* __restrict__ csr_val) {
    int stride = gridDim.x * blockDim.x;
    for (int e = blockIdx.x * blockDim.x + threadIdx.x; e < NNZ; e += stride) {
        int r = rows[e];
        int pos = atomicAdd(&cursor[r], 1);
        csr_col[pos] = cols[e];
        csr_val[pos] = vals[e];
    }
}

// ---------------------------------------------------------------------------
// SpMM (CSR): one wave per row, lane = dim. No atomics; empty rows write 0.
// FIRST: gather from the two embedding tables instead of a concat buffer.
// ---------------------------------------------------------------------------
template <bool FIRST>
__global__ void spmm_kernel(const int* __restrict__ rowptr,
                            const int* __restrict__ csr_col,
                            const float* __restrict__ csr_val,
                            const float* __restrict__ x,
                            const float* __restrict__ user_emb,
                            const float* __restrict__ item_emb,
                            float* __restrict__ y) {
    const int lane = threadIdx.x & 63;
    const int r = (int)((blockIdx.x * blockDim.x + threadIdx.x) >> 6);
    if (r >= N_NODES) return;
    int e   = rowptr[r];
    int end = rowptr[r + 1];
    float a0 = 0.f, a1 = 0.f;

    auto gather = [&](int c) -> float {
        if (FIRST) {
            return (c < NUM_USERS) ? user_emb[(int64_t)c * DIM + lane]
                                   : item_emb[(int64_t)(c - NUM_USERS) * DIM + lane];
        } else {
            return x[(int64_t)c * DIM + lane];
        }
    };

    for (; e + 1 < end; e += 2) {        // 2-way unroll: 2 gathers in flight
        int c0 = csr_col[e], c1 = csr_col[e + 1];
        float v0 = csr_val[e], v1 = csr_val[e + 1];
        a0 += v0 * gather(c0);
        a1 += v1 * gather(c1);
    }
    if (e < end) a0 += csr_val[e] * gather(csr_col[e]);
    y[(int64_t)r * DIM + lane] = a0 + a1;
}

// ---------------------------------------------------------------------------
// Per-batch accumulator update: acc[i] (+)= x[row(i)]
// i in [0, 2*BATCH): first BATCH are users, rest are items.
// ---------------------------------------------------------------------------
template <bool FIRST>
__global__ void gather_acc_kernel(const int* __restrict__ user_idx,
                                  const int* __restrict__ item_idx,
                                  const float* __restrict__ x,
                                  const float* __restrict__ user_emb,
                                  const float* __restrict__ item_emb,
                                  float* __restrict__ acc) {
    const int lane = threadIdx.x & 63;
    const int i = (int)((blockIdx.x * blockDim.x + threadIdx.x) >> 6);
    if (i >= 2 * BATCH) return;
    float v;
    if (FIRST) {
        if (i < BATCH) v = user_emb[(int64_t)user_idx[i] * DIM + lane];
        else           v = item_emb[(int64_t)item_idx[i - BATCH] * DIM + lane];
        acc[(int64_t)i * DIM + lane] = v;
    } else {
        int row = (i < BATCH) ? user_idx[i] : (NUM_USERS + item_idx[i - BATCH]);
        v = x[(int64_t)row * DIM + lane];
        acc[(int64_t)i * DIM + lane] += v;
    }
}

// ---------------------------------------------------------------------------
// Output: rating dot + scaled user/item embeddings
// ---------------------------------------------------------------------------
__global__ void out_kernel(const float* __restrict__ acc, float* __restrict__ out) {
    const int lane = threadIdx.x & 63;
    const int b = (int)((blockIdx.x * blockDim.x + threadIdx.x) >> 6);
    if (b >= BATCH) return;
    float uv = acc[(int64_t)b * DIM + lane] * 0.25f;
    float iv = acc[(int64_t)(BATCH + b) * DIM + lane] * 0.25f;
    out[(int64_t)BATCH + (int64_t)b * DIM + lane] = uv;
    out[(int64_t)BATCH + (int64_t)BATCH * DIM + (int64_t)b * DIM + lane] = iv;
    float p = uv * iv;
    #pragma unroll
    for (int off = 32; off >= 1; off >>= 1) p += __shfl_down(p, off, 64);
    if (lane == 0) out[b] = p;
}

// ---------------------------------------------------------------------------
extern "C" void kernel_launch(void* const* d_in, const int* in_sizes, int n_in,
                              void* d_out, int out_size, void* d_ws, size_t ws_size,
                              hipStream_t stream) {
    const int*   user_idx = (const int*)  d_in[0];
    const int*   item_idx = (const int*)  d_in[1];
    const int*   rows     = (const int*)  d_in[2];
    const int*   cols     = (const int*)  d_in[3];
    const float* vals     = (const float*)d_in[4];
    const float* user_emb = (const float*)d_in[5];
    const float* item_emb = (const float*)d_in[6];
    float*       out      = (float*)d_out;

    // ---- workspace layout (256B-aligned chunks) ----
    char* base = (char*)d_ws;
    size_t off = 0;
    auto alloc = [&](size_t bytes) -> char* {
        char* p = base + off;
        off = (off + bytes + 255) & ~(size_t)255;
        return p;
    };
    int*   cnt     = (int*)  alloc((size_t)(N_NODES + 1) * sizeof(int));
    int*   rowptr  = (int*)  alloc((size_t)(N_NODES + 1) * sizeof(int));
    int*   cursor  = (int*)  alloc((size_t)N_NODES * sizeof(int));
    int*   blksum  = (int*)  alloc((size_t)NBLK * sizeof(int));
    int*   csr_col = (int*)  alloc((size_t)NNZ * sizeof(int));
    float* csr_val = (float*)alloc((size_t)NNZ * sizeof(float));
    float* buf0    = (float*)alloc((size_t)N_NODES * DIM * sizeof(float));
    float* buf1    = (float*)alloc((size_t)N_NODES * DIM * sizeof(float));
    float* acc     = (float*)alloc((size_t)2 * BATCH * DIM * sizeof(float));

    const int TB = 256;

    // ---- CSR build ----
    hipMemsetAsync(cnt, 0, (size_t)(N_NODES + 1) * sizeof(int), stream);
    hist_kernel<<<2048, TB, 0, stream>>>(rows, cnt);
    scan_block_kernel<<<NBLK, SCAN_B, 0, stream>>>(cnt, rowptr, blksum);
    scan_top_kernel<<<1, SCAN_B, 0, stream>>>(blksum);
    scan_fix_kernel<<<(N_NODES + TB - 1) / TB, TB, 0, stream>>>(rowptr, blksum, cursor);
    scatter_kernel<<<2048, TB, 0, stream>>>(rows, cols, vals, cursor, csr_col, csr_val);

    // ---- propagation ----
    const int spmmBlocks = (N_NODES * 64 + TB - 1) / TB;       // 1 wave per row
    const int gathBlocks = (2 * BATCH * 64 + TB - 1) / TB;

    // acc = layer-0 rows
    gather_acc_kernel<true><<<gathBlocks, TB, 0, stream>>>(
        user_idx, item_idx, nullptr, user_emb, item_emb, acc);

    // layer 1: emb -> buf0
    spmm_kernel<true><<<spmmBlocks, TB, 0, stream>>>(
        rowptr, csr_col, csr_val, nullptr, user_emb, item_emb, buf0);
    gather_acc_kernel<false><<<gathBlocks, TB, 0, stream>>>(
        user_idx, item_idx, buf0, nullptr, nullptr, acc);

    // layer 2: buf0 -> buf1
    spmm_kernel<false><<<spmmBlocks, TB, 0, stream>>>(
        rowptr, csr_col, csr_val, buf0, nullptr, nullptr, buf1);
    gather_acc_kernel<false><<<gathBlocks, TB, 0, stream>>>(
        user_idx, item_idx, buf1, nullptr, nullptr, acc);

    // layer 3: buf1 -> buf0
    spmm_kernel<false><<<spmmBlocks, TB, 0, stream>>>(
        rowptr, csr_col, csr_val, buf1, nullptr, nullptr, buf0);
    gather_acc_kernel<false><<<gathBlocks, TB, 0, stream>>>(
        user_idx, item_idx, buf0, nullptr, nullptr, acc);

    // ---- output ----
    out_kernel<<<(BATCH * 64 + TB - 1) / TB, TB, 0, stream>>>(acc, out);
}